// Round 14
// baseline (161.544 us; speedup 1.0000x reference)
//
#include <hip/hip_runtime.h>
#include <hip/hip_fp16.h>
#include <math.h>

#define NEG_SLOPE 0.2f
#define TILE 16   // nodes per prep/post block
#define BKB2 8    // bucket = dst >> 8  (256 nodes per bucket)
#define CHUNK 16384

// ==================== init: zero bcnt + fold alphas + pack W + MLP =========
__global__ void k_init(
    const float* __restrict__ W1, const float* __restrict__ as1,
    const float* __restrict__ ad1,
    const float* __restrict__ W2, const float* __restrict__ as2,
    const float* __restrict__ ad2,
    const float* __restrict__ lw1, const float* __restrict__ lb1,
    const float* __restrict__ lw2, const float* __restrict__ lb2,
    float* __restrict__ wsd1, float* __restrict__ wsd2,
    float* __restrict__ weff,
    unsigned int* __restrict__ whalf1, unsigned int* __restrict__ whalf2,
    int* __restrict__ bcnt, int NBK)
{
    int t = threadIdx.x;                      // 832 threads
    if (t <= NBK) bcnt[t] = 0;
    if (t < 768) {
        int layer = (t >= 384);
        int r = t - layer * 384;
        int k = r / 12, j = r - k * 12;
        const float* W = layer ? W2 : W1;
        const float* a = (j < 6) ? (layer ? as2 : as1) : (layer ? ad2 : ad1);
        int h = (j < 6) ? j : j - 6;
        float acc = 0.f;
        #pragma unroll
        for (int c = 0; c < 32; ++c)
            acc = fmaf(W[k * 192 + h * 32 + c], a[h * 32 + c], acc);
        (layer ? wsd2 : wsd1)[k * 12 + j] = acc;
    } else {
        int i = t - 768;                      // 0..63
        float acc = 0.f;
        for (int o = 0; o < 64; ++o) acc += lw1[i * 64 + o] * lw2[o];
        weff[i] = acc;
        if (i == 0) {
            float b = lb2[0];
            for (int o = 0; o < 64; ++o) b += lb1[o] * lw2[o];
            weff[64] = b;
        }
    }
    if (t < 384) {
        int layer = (t >= 192);
        int col = t - layer * 192;
        const float* W = layer ? W2 : W1;
        unsigned int* dst = layer ? whalf2 : whalf1;
        #pragma unroll
        for (int i = 0; i < 16; ++i) {
            __half2 p = __floats2half2_rn(W[(2 * i) * 192 + col],
                                          W[(2 * i + 1) * 192 + col]);
            dst[col * 16 + i] = *(unsigned int*)&p;
        }
    }
}

// ==================== hist (edge buckets) + layer-1 prep, fused ============
__global__ __launch_bounds__(256) void k_hist_prep(
    const int* __restrict__ g, int E, int* __restrict__ bcnt,
    int* __restrict__ blockbase, int NBK, int NBLK,
    const float* __restrict__ xf, const int* __restrict__ gidx,
    const float* __restrict__ wsd, __half* __restrict__ xp,
    float* __restrict__ asrc, float* __restrict__ adst, int N)
{
    __shared__ int hist[256];
    __shared__ float xs[TILE * 33];
    __shared__ int   rows[TILE];
    __shared__ float wsd_s[384];
    const int t = threadIdx.x;
    if (blockIdx.x < NBLK) {
        const int blk = blockIdx.x;
        hist[t] = 0;
        __syncthreads();
        const int base = blk * CHUNK;
        const int end = min(base + CHUNK, E);
        for (int e = base + t; e < end; e += 256)
            atomicAdd(&hist[g[E + e] >> BKB2], 1);
        __syncthreads();
        if (t < NBK) {
            int c = hist[t];
            blockbase[blk * NBK + t] = c ? atomicAdd(&bcnt[t], c) : 0;
        }
    } else {
        const int n0 = (blockIdx.x - NBLK) * TILE;
        for (int i = t; i < 384; i += 256) wsd_s[i] = wsd[i];
        if (t < TILE) {
            int n = n0 + t;
            rows[t] = (n < N) ? gidx[n] : -1;
        }
        __syncthreads();
        if (t < TILE * 8) {
            int m = t >> 3, q = t & 7;
            int r = rows[m];
            float4 v = (r >= 0) ? *(const float4*)(xf + (size_t)r * 32 + q * 4)
                                : make_float4(0.f, 0.f, 0.f, 0.f);
            float* dst = xs + m * 33 + q * 4;
            dst[0] = v.x; dst[1] = v.y; dst[2] = v.z; dst[3] = v.w;
            if (r >= 0) {
                __half2 p0 = __floats2half2_rn(v.x, v.y);
                __half2 p1 = __floats2half2_rn(v.z, v.w);
                uint2 u; u.x = *(unsigned int*)&p0; u.y = *(unsigned int*)&p1;
                *(uint2*)((unsigned int*)xp + (size_t)(n0 + m) * 16 + q * 2) = u;
            }
        }
        __syncthreads();
        if (t < 192) {
            const int m = t / 12, j = t - m * 12;
            const int n = n0 + m;
            if (n < N) {
                const float* xr = xs + m * 33;
                float a = 0.f;
                #pragma unroll
                for (int k = 0; k < 32; ++k)
                    a = fmaf(xr[k], wsd_s[k * 12 + j], a);
                if (j < 6) asrc[(size_t)n * 8 + j] = a;
                else       adst[(size_t)n * 8 + (j - 6)] = a;
            }
        }
    }
}

// in-block exclusive scan of bcnt (NBK <= 256), 256 threads
__device__ __forceinline__ int scan_excl_256(int v, int* wsum)
{
    const int t = threadIdx.x, lane = t & 63, w = t >> 6;
    int incl = v;
    #pragma unroll
    for (int off = 1; off < 64; off <<= 1) {
        int u = __shfl_up(incl, off);
        if (lane >= off) incl += u;
    }
    if (lane == 63) wsum[w] = incl;
    __syncthreads();
    int base = 0;
    for (int q = 0; q < w; ++q) base += wsum[q];
    return base + incl - v;
}

// bin: LDS cursors from (inline-scanned) bcnt + reserved blockbase
__global__ __launch_bounds__(256) void k_bin2(
    const int* __restrict__ g, int E, const int* __restrict__ bcnt,
    const int* __restrict__ blockbase, int* __restrict__ pairs, int NBK)
{
    __shared__ int cur[256];
    __shared__ int wsum[4];
    const int t = threadIdx.x, blk = blockIdx.x;
    const int v = (t < NBK) ? bcnt[t] : 0;
    const int excl = scan_excl_256(v, wsum);
    if (t < NBK) cur[t] = excl + blockbase[blk * NBK + t];
    __syncthreads();
    const int base = blk * CHUNK;
    const int end = min(base + CHUNK, E);
    for (int e = base + t; e < end; e += 256) {
        int s = g[e], d = g[E + e];
        int pos = atomicAdd(&cur[d >> BKB2], 1);
        pairs[pos] = (s << 8) | (d & 255);
    }
}

// build: one block per 256-node bucket
__global__ __launch_bounds__(256) void k_build(
    const int* __restrict__ pairs, const int* __restrict__ bcnt,
    int* __restrict__ rowptr, int* __restrict__ deg, int* __restrict__ adj,
    int N, int NBK)
{
    __shared__ int cnt[256];
    __shared__ int cur[256];
    __shared__ int wsum[4];
    __shared__ int lohi[2];
    const int b = blockIdx.x, t = threadIdx.x;
    {
        const int v = (t < NBK) ? bcnt[t] : 0;
        const int excl = scan_excl_256(v, wsum);
        if (t == b) { lohi[0] = excl; lohi[1] = excl + v; }
    }
    cnt[t] = 0;
    __syncthreads();
    const int lo = lohi[0], hi = lohi[1];
    for (int i = lo + t; i < hi; i += 256)
        atomicAdd(&cnt[pairs[i] & 255], 1);
    __syncthreads();
    const int v = cnt[t];
    __syncthreads();                          // wsum reuse
    const int excl = scan_excl_256(v, wsum);
    const int node = b * 256 + t;
    const int abase = lo + b * 256;
    if (node < N) {
        const int rp = abase + excl + t;
        rowptr[node] = rp;
        deg[node] = v + 1;
        adj[rp] = node;                       // self-loop first
        cur[t] = rp + 1;
    } else cur[t] = 0;
    __syncthreads();
    for (int i = lo + t; i < hi; i += 256) {
        int p = pairs[i];
        int pos = atomicAdd(&cur[p & 255], 1);
        adj[pos] = p >> 8;
    }
}

// ==================== gather: z_h[c] = sum_e w_eh * x[src_e][c] =============
// TWO nodes per 64-lane wave (one per half; lane = channel = edge slot).
// Weight phase: 6 f32 exp -> pack to 3 half2 -> 3 cndmask (invalid slots
// zeroed) -> hadd2 den accumulate.  Record = float4 {byte_off, w01,w23,w45}.
// Gather body per wave-instr covers 2 edges: 1 ds_read_b128 + 1 ushort load
// + 3 pk_fma; trip padded to x2 only.  Den reduce: 3 packed half2 regs
// (15 shfl + 15 hadd2).  z acc fp16, den fp16 (bounded by 128; rel ~1e-3).
// No max-subtraction (scores are O(0.1); softmax is shift-invariant).
__global__ __launch_bounds__(256) void k_gat(
    const int* __restrict__ rowptr, const int* __restrict__ deg,
    const int* __restrict__ adj,
    const float* __restrict__ asrc, const float* __restrict__ adst,
    const __half* __restrict__ xp, __half* __restrict__ zn, int N)
{
    __shared__ float4 st[4][2][32];
    const int wv = threadIdx.x >> 6;
    const int lane = threadIdx.x & 63;
    const int half = lane >> 5;
    const int c = lane & 31;                  // channel == edge slot
    const int n = blockIdx.x * 8 + wv * 2 + half;
    const bool nvalid = (n < N);
    const int nsafe = nvalid ? n : 0;

    const float* adr = adst + (size_t)nsafe * 8;
    const float ad0 = adr[0], ad1 = adr[1], ad2 = adr[2];
    const float ad3 = adr[3], ad4 = adr[4], ad5 = adr[5];

    const int start = rowptr[nsafe];
    const int dg = nvalid ? deg[nsafe] : 1;
    const int dgmax = max(dg, __shfl_xor(dg, 32));
    const char* xcb = (const char*)xp + c * 2;

    const __half2 hzero = __float2half2_rn(0.f);
    __half2 acc0 = hzero, acc1 = hzero, acc2 = hzero;
    __half2 dlA = hzero, dlB = hzero, dlC = hzero;

    for (int base = 0; base < dgmax; base += 32) {
        const int rem = dg - base;
        const bool valid = nvalid && (c < rem);
        const int s = valid ? adj[start + base + c] : 0;
        const float4* a4 = (const float4*)(asrc + (size_t)s * 8);
        const float4 A = a4[0], Bv = a4[1];
        float v0 = A.x + ad0, v1 = A.y + ad1, v2 = A.z + ad2;
        float v3 = A.w + ad3, v4 = Bv.x + ad4, v5 = Bv.y + ad5;
        v0 = fmaxf(v0, NEG_SLOPE * v0); v1 = fmaxf(v1, NEG_SLOPE * v1);
        v2 = fmaxf(v2, NEG_SLOPE * v2); v3 = fmaxf(v3, NEG_SLOPE * v3);
        v4 = fmaxf(v4, NEG_SLOPE * v4); v5 = fmaxf(v5, NEG_SLOPE * v5);
        __half2 w01 = __floats2half2_rn(__expf(v0), __expf(v1));
        __half2 w23 = __floats2half2_rn(__expf(v2), __expf(v3));
        __half2 w45 = __floats2half2_rn(__expf(v4), __expf(v5));
        if (!valid) { w01 = hzero; w23 = hzero; w45 = hzero; }
        dlA = __hadd2(dlA, w01);
        dlB = __hadd2(dlB, w23);
        dlC = __hadd2(dlC, w45);
        float4 rec;
        rec.x = __int_as_float(s * 64);       // byte offset of fp16 x row
        rec.y = *(const float*)&w01;
        rec.z = *(const float*)&w23;
        rec.w = *(const float*)&w45;
        st[wv][half][c] = rec;                // all 64 lanes write own slot

        // gather this chunk; trip = max over both halves, padded x2; slots
        // past a node's rem carry zero weights, so they're harmless.
        const int cntw = min(32, dgmax - base);
        const int nh = (cntw + 1) & ~1;
        for (int i = 0; i < nh; i += 2) {
            #pragma unroll
            for (int q = 0; q < 2; ++q) {
                const float4 r = st[wv][half][i + q];
                const __half xval = *(const __half*)(xcb + __float_as_int(r.x));
                const __half2 xv2 = __half2half2(xval);
                acc0 = __hfma2(*(const __half2*)&r.y, xv2, acc0);
                acc1 = __hfma2(*(const __half2*)&r.z, xv2, acc1);
                acc2 = __hfma2(*(const __half2*)&r.w, xv2, acc2);
            }
        }
    }
    // denominators: reduce packed half2 over the 32 edge-slots of MY half
    #pragma unroll
    for (int o = 1; o <= 16; o <<= 1) {
        int bA = __shfl_xor(*(const int*)&dlA, o);
        int bB = __shfl_xor(*(const int*)&dlB, o);
        int bC = __shfl_xor(*(const int*)&dlC, o);
        dlA = __hadd2(dlA, *(const __half2*)&bA);
        dlB = __hadd2(dlB, *(const __half2*)&bB);
        dlC = __hadd2(dlC, *(const __half2*)&bC);
    }
    if (nvalid) {
        const float r0 = 1.f / __low2float(dlA);
        const float r1 = 1.f / __high2float(dlA);
        const float r2 = 1.f / __low2float(dlB);
        const float r3 = 1.f / __high2float(dlB);
        const float r4 = 1.f / __low2float(dlC);
        const float r5 = 1.f / __high2float(dlC);
        __half* zr = zn + (size_t)n * 192 + c;
        zr[0]   = __float2half(__low2float(acc0)  * r0);
        zr[32]  = __float2half(__high2float(acc0) * r1);
        zr[64]  = __float2half(__low2float(acc1)  * r2);
        zr[96]  = __float2half(__high2float(acc1) * r3);
        zr[128] = __float2half(__low2float(acc2)  * r4);
        zr[160] = __float2half(__high2float(acc2) * r5);
    }
}

// ==================== post: y = (1/6) sum_h znorm_h . W_h + b ===============
// FUSE=0: also computes next layer's alphas from y in-LDS (fused prep) and
// writes fp16 y rows.  FUSE=1: fused MLP head + sigmoid.
template<int FUSE>
__global__ __launch_bounds__(192) void k_post(
    const __half* __restrict__ zn, const unsigned int* __restrict__ whalf,
    const float* __restrict__ bias, __half* __restrict__ yout,
    const float* __restrict__ wsd,
    float* __restrict__ asrc, float* __restrict__ adst,
    const int* __restrict__ user, const float* __restrict__ u_table,
    const float* __restrict__ weff, float* __restrict__ outp, int N)
{
    __shared__ unsigned int znl[TILE][96];
    __shared__ float part[TILE][192];
    __shared__ float ys[TILE][33];
    __shared__ float wsd_s[384];
    const int t = threadIdx.x;
    const int h = t >> 5, c = t & 31;
    const int n0 = blockIdx.x * TILE;

    const uint4* wq = (const uint4*)(whalf + (size_t)t * 16);
    const uint4 w0 = wq[0], w1 = wq[1], w2 = wq[2], w3 = wq[3];
    if (FUSE == 0)
        for (int i = t; i < 384; i += 192) wsd_s[i] = wsd[i];

    {   // stage znorm tile: 16 rows x 96 dwords; thread loads 8 dwords
        const int m = t / 12, slot = t - m * 12;
        const int n = n0 + m;
        if (n < N) {
            const uint4* src = (const uint4*)((const unsigned int*)zn
                               + (size_t)n * 96 + slot * 8);
            uint4 a = src[0], b = src[1];
            uint4* d = (uint4*)&znl[m][slot * 8];
            d[0] = a; d[1] = b;
        }
    }
    __syncthreads();

    #define DOT4(W) { \
        unsigned int zz0 = zp[0], zz1 = zp[1], zz2 = zp[2], zz3 = zp[3]; \
        acc2 = __hfma2(*(__half2*)&zz0, *(__half2*)&W.x, acc2); \
        acc2 = __hfma2(*(__half2*)&zz1, *(__half2*)&W.y, acc2); \
        acc2 = __hfma2(*(__half2*)&zz2, *(__half2*)&W.z, acc2); \
        acc2 = __hfma2(*(__half2*)&zz3, *(__half2*)&W.w, acc2); zp += 4; }

    #pragma unroll 4
    for (int m = 0; m < TILE; ++m) {
        const unsigned int* zp = &znl[m][h * 16];
        __half2 acc2 = __float2half2_rn(0.f);
        DOT4(w0) DOT4(w1) DOT4(w2) DOT4(w3)
        part[m][t] = __low2float(acc2) + __high2float(acc2);
    }
    #undef DOT4
    __syncthreads();

    #pragma unroll
    for (int mb = 0; mb < 3; ++mb) {
        const int m = mb * 6 + h;             // h in 0..5 -> m in 0..17
        const int n = n0 + m;
        if (m < TILE && n < N) {
            const float y = (part[m][c] + part[m][32 + c] + part[m][64 + c]
                           + part[m][96 + c] + part[m][128 + c]
                           + part[m][160 + c]) * (1.f / 6.f) + bias[c];
            if (FUSE == 0) {
                yout[(size_t)n * 32 + c] = __float2half(y);
                ys[m][c] = y;
            } else {
                const float u = u_table[(size_t)user[n] * 32 + c];
                float p = fmaf(y, weff[32 + c], u * weff[c]);
                #pragma unroll
                for (int o = 16; o > 0; o >>= 1) p += __shfl_xor(p, o);
                if (c == 0) outp[n] = 1.f / (1.f + __expf(-(p + weff[64])));
            }
        }
    }
    if (FUSE == 0) {                          // fused next-layer alpha prep
        __syncthreads();
        const int m = t / 12, j = t - m * 12;
        const int n = n0 + m;
        if (n < N) {
            const float* yr = ys[m];
            float a = 0.f;
            #pragma unroll
            for (int k = 0; k < 32; ++k) a = fmaf(yr[k], wsd_s[k * 12 + j], a);
            if (j < 6) asrc[(size_t)n * 8 + j] = a;
            else       adst[(size_t)n * 8 + (j - 6)] = a;
        }
    }
}

// ==================== launch ================================================

extern "C" void kernel_launch(void* const* d_in, const int* in_sizes, int n_in,
                              void* d_out, int out_size, void* d_ws, size_t ws_size,
                              hipStream_t stream)
{
    const int*   user    = (const int*)  d_in[0];
    const int*   item    = (const int*)  d_in[1];
    const int*   graph   = (const int*)  d_in[2];
    const float* u_table = (const float*)d_in[3];
    const float* i_table = (const float*)d_in[4];
    const float* W1      = (const float*)d_in[5];
    const float* a_src1  = (const float*)d_in[6];
    const float* a_dst1  = (const float*)d_in[7];
    const float* b1      = (const float*)d_in[8];
    const float* W2      = (const float*)d_in[9];
    const float* a_src2  = (const float*)d_in[10];
    const float* a_dst2  = (const float*)d_in[11];
    const float* b2      = (const float*)d_in[12];
    const float* lw1     = (const float*)d_in[13];
    const float* lb1     = (const float*)d_in[14];
    const float* lw2     = (const float*)d_in[15];
    const float* lb2     = (const float*)d_in[16];

    const int B  = in_sizes[0];
    const int N  = B;
    const int E  = in_sizes[2] / 2;
    const int Et = E + N;
    const int NBK = (N + 255) / 256;
    const int NBLK = (E + CHUNK - 1) / CHUNK;

    float* ws = (float*)d_ws;
    size_t off = 0;
    __half* xp1   = (__half*)(ws + off); off += (size_t)N * 16;  // N*32 halves
    __half* y1h   = (__half*)(ws + off); off += (size_t)N * 16;
    __half* zn    = (__half*)(ws + off); off += (size_t)N * 96;  // N*192 halves
    float* asrc   = ws + off; off += (size_t)N * 8;
    float* adst   = ws + off; off += (size_t)N * 8;
    float* wsd1   = ws + off; off += 384;
    float* wsd2   = ws + off; off += 384;
    float* weff   = ws + off; off += 128;
    unsigned int* whalf1 = (unsigned int*)(ws + off); off += 3072;
    unsigned int* whalf2 = (unsigned int*)(ws + off); off += 3072;
    int*   deg    = (int*)(ws + off); off += N;
    int*   rowptr = (int*)(ws + off); off += N;
    int*   bcnt   = (int*)(ws + off); off += NBK + 1;
    int*   bbase  = (int*)(ws + off); off += (size_t)NBLK * NBK;
    int*   adj    = (int*)(ws + off); off += Et + 2;
    int*   pairs  = (int*)(ws + off); off += E;

    const int ggrid = (N + 7) / 8;
    const int pgrid = (N + TILE - 1) / TILE;

    // L1: zero bcnt + setup (wsd, whalf, weff)
    hipLaunchKernelGGL(k_init, dim3(1), dim3(832), 0, stream,
        W1, a_src1, a_dst1, W2, a_src2, a_dst2,
        lw1, lb1, lw2, lb2, wsd1, wsd2, weff, whalf1, whalf2, bcnt, NBK);
    // L2: edge histogram + layer-1 prep (independent work, one dispatch)
    hipLaunchKernelGGL(k_hist_prep, dim3(NBLK + pgrid), dim3(256), 0, stream,
        graph, E, bcnt, bbase, NBK, NBLK,
        i_table, item, wsd1, xp1, asrc, adst, N);
    // L3: bin packed pairs (inline bucket scan)
    hipLaunchKernelGGL(k_bin2, dim3(NBLK), dim3(256), 0, stream,
        graph, E, bcnt, bbase, pairs, NBK);
    // L4: per-bucket CSR build (inline bucket scan)
    hipLaunchKernelGGL(k_build, dim3(NBK), dim3(256), 0, stream,
        pairs, bcnt, rowptr, deg, adj, N, NBK);
    // L5: layer-1 gather
    hipLaunchKernelGGL(k_gat, dim3(ggrid), dim3(256), 0, stream,
        rowptr, deg, adj, asrc, adst, xp1, zn, N);
    // L6: layer-1 post + fused layer-2 alpha prep
    hipLaunchKernelGGL(k_post<0>, dim3(pgrid), dim3(192), 0, stream,
        zn, whalf1, b1, y1h, wsd2, asrc, adst,
        (const int*)nullptr, (const float*)nullptr,
        (const float*)nullptr, (float*)nullptr, N);
    // L7: layer-2 gather
    hipLaunchKernelGGL(k_gat, dim3(ggrid), dim3(256), 0, stream,
        rowptr, deg, adj, asrc, adst, y1h, zn, N);
    // L8: layer-2 post + fused MLP head + sigmoid
    hipLaunchKernelGGL(k_post<1>, dim3(pgrid), dim3(192), 0, stream,
        zn, whalf2, b2, (__half*)nullptr, (const float*)nullptr,
        (float*)nullptr, (float*)nullptr,
        user, u_table, weff, (float*)d_out, N);
}

// Round 15
// 152.540 us; speedup vs baseline: 1.0590x; 1.0590x over previous
//
#include <hip/hip_runtime.h>
#include <hip/hip_fp16.h>
#include <math.h>

#define NEG_SLOPE 0.2f
#define TILE 16   // nodes per prep/post block
#define BKB2 8    // bucket = dst >> 8  (256 nodes per bucket)
#define CHUNK 16384

// ==================== init: zero bcnt + fold alphas + pack W + MLP =========
__global__ void k_init(
    const float* __restrict__ W1, const float* __restrict__ as1,
    const float* __restrict__ ad1,
    const float* __restrict__ W2, const float* __restrict__ as2,
    const float* __restrict__ ad2,
    const float* __restrict__ lw1, const float* __restrict__ lb1,
    const float* __restrict__ lw2, const float* __restrict__ lb2,
    float* __restrict__ wsd1, float* __restrict__ wsd2,
    float* __restrict__ weff,
    unsigned int* __restrict__ whalf1, unsigned int* __restrict__ whalf2,
    int* __restrict__ bcnt, int NBK)
{
    int t = threadIdx.x;                      // 832 threads
    if (t <= NBK) bcnt[t] = 0;
    if (t < 768) {
        int layer = (t >= 384);
        int r = t - layer * 384;
        int k = r / 12, j = r - k * 12;
        const float* W = layer ? W2 : W1;
        const float* a = (j < 6) ? (layer ? as2 : as1) : (layer ? ad2 : ad1);
        int h = (j < 6) ? j : j - 6;
        float acc = 0.f;
        #pragma unroll
        for (int c = 0; c < 32; ++c)
            acc = fmaf(W[k * 192 + h * 32 + c], a[h * 32 + c], acc);
        (layer ? wsd2 : wsd1)[k * 12 + j] = acc;
    } else {
        int i = t - 768;                      // 0..63
        float acc = 0.f;
        for (int o = 0; o < 64; ++o) acc += lw1[i * 64 + o] * lw2[o];
        weff[i] = acc;
        if (i == 0) {
            float b = lb2[0];
            for (int o = 0; o < 64; ++o) b += lb1[o] * lw2[o];
            weff[64] = b;
        }
    }
    if (t < 384) {
        int layer = (t >= 192);
        int col = t - layer * 192;
        const float* W = layer ? W2 : W1;
        unsigned int* dst = layer ? whalf2 : whalf1;
        #pragma unroll
        for (int i = 0; i < 16; ++i) {
            __half2 p = __floats2half2_rn(W[(2 * i) * 192 + col],
                                          W[(2 * i + 1) * 192 + col]);
            dst[col * 16 + i] = *(unsigned int*)&p;
        }
    }
}

// ==================== hist (edge buckets) + layer-1 prep, fused ============
__global__ __launch_bounds__(256) void k_hist_prep(
    const int* __restrict__ g, int E, int* __restrict__ bcnt,
    int* __restrict__ blockbase, int NBK, int NBLK,
    const float* __restrict__ xf, const int* __restrict__ gidx,
    const float* __restrict__ wsd, __half* __restrict__ xp,
    float* __restrict__ asrc, float* __restrict__ adst, int N)
{
    __shared__ int hist[256];
    __shared__ float xs[TILE * 33];
    __shared__ int   rows[TILE];
    __shared__ float wsd_s[384];
    const int t = threadIdx.x;
    if (blockIdx.x < NBLK) {
        const int blk = blockIdx.x;
        hist[t] = 0;
        __syncthreads();
        const int base = blk * CHUNK;
        const int end = min(base + CHUNK, E);
        for (int e = base + t; e < end; e += 256)
            atomicAdd(&hist[g[E + e] >> BKB2], 1);
        __syncthreads();
        if (t < NBK) {
            int c = hist[t];
            blockbase[blk * NBK + t] = c ? atomicAdd(&bcnt[t], c) : 0;
        }
    } else {
        const int n0 = (blockIdx.x - NBLK) * TILE;
        for (int i = t; i < 384; i += 256) wsd_s[i] = wsd[i];
        if (t < TILE) {
            int n = n0 + t;
            rows[t] = (n < N) ? gidx[n] : -1;
        }
        __syncthreads();
        if (t < TILE * 8) {
            int m = t >> 3, q = t & 7;
            int r = rows[m];
            float4 v = (r >= 0) ? *(const float4*)(xf + (size_t)r * 32 + q * 4)
                                : make_float4(0.f, 0.f, 0.f, 0.f);
            float* dst = xs + m * 33 + q * 4;
            dst[0] = v.x; dst[1] = v.y; dst[2] = v.z; dst[3] = v.w;
            if (r >= 0) {
                __half2 p0 = __floats2half2_rn(v.x, v.y);
                __half2 p1 = __floats2half2_rn(v.z, v.w);
                uint2 u; u.x = *(unsigned int*)&p0; u.y = *(unsigned int*)&p1;
                *(uint2*)((unsigned int*)xp + (size_t)(n0 + m) * 16 + q * 2) = u;
            }
        }
        __syncthreads();
        if (t < 192) {
            const int m = t / 12, j = t - m * 12;
            const int n = n0 + m;
            if (n < N) {
                const float* xr = xs + m * 33;
                float a = 0.f;
                #pragma unroll
                for (int k = 0; k < 32; ++k)
                    a = fmaf(xr[k], wsd_s[k * 12 + j], a);
                if (j < 6) asrc[(size_t)n * 8 + j] = a;
                else       adst[(size_t)n * 8 + (j - 6)] = a;
            }
        }
    }
}

// in-block exclusive scan of bcnt (NBK <= 256), 256 threads
__device__ __forceinline__ int scan_excl_256(int v, int* wsum)
{
    const int t = threadIdx.x, lane = t & 63, w = t >> 6;
    int incl = v;
    #pragma unroll
    for (int off = 1; off < 64; off <<= 1) {
        int u = __shfl_up(incl, off);
        if (lane >= off) incl += u;
    }
    if (lane == 63) wsum[w] = incl;
    __syncthreads();
    int base = 0;
    for (int q = 0; q < w; ++q) base += wsum[q];
    return base + incl - v;
}

// bin: LDS cursors from (inline-scanned) bcnt + reserved blockbase
__global__ __launch_bounds__(256) void k_bin2(
    const int* __restrict__ g, int E, const int* __restrict__ bcnt,
    const int* __restrict__ blockbase, int* __restrict__ pairs, int NBK)
{
    __shared__ int cur[256];
    __shared__ int wsum[4];
    const int t = threadIdx.x, blk = blockIdx.x;
    const int v = (t < NBK) ? bcnt[t] : 0;
    const int excl = scan_excl_256(v, wsum);
    if (t < NBK) cur[t] = excl + blockbase[blk * NBK + t];
    __syncthreads();
    const int base = blk * CHUNK;
    const int end = min(base + CHUNK, E);
    for (int e = base + t; e < end; e += 256) {
        int s = g[e], d = g[E + e];
        int pos = atomicAdd(&cur[d >> BKB2], 1);
        pairs[pos] = (s << 8) | (d & 255);
    }
}

// build: one block per 256-node bucket
__global__ __launch_bounds__(256) void k_build(
    const int* __restrict__ pairs, const int* __restrict__ bcnt,
    int* __restrict__ rowptr, int* __restrict__ deg, int* __restrict__ adj,
    int N, int NBK)
{
    __shared__ int cnt[256];
    __shared__ int cur[256];
    __shared__ int wsum[4];
    __shared__ int lohi[2];
    const int b = blockIdx.x, t = threadIdx.x;
    {
        const int v = (t < NBK) ? bcnt[t] : 0;
        const int excl = scan_excl_256(v, wsum);
        if (t == b) { lohi[0] = excl; lohi[1] = excl + v; }
    }
    cnt[t] = 0;
    __syncthreads();
    const int lo = lohi[0], hi = lohi[1];
    for (int i = lo + t; i < hi; i += 256)
        atomicAdd(&cnt[pairs[i] & 255], 1);
    __syncthreads();
    const int v = cnt[t];
    __syncthreads();                          // wsum reuse
    const int excl = scan_excl_256(v, wsum);
    const int node = b * 256 + t;
    const int abase = lo + b * 256;
    if (node < N) {
        const int rp = abase + excl + t;
        rowptr[node] = rp;
        deg[node] = v + 1;
        adj[rp] = node;                       // self-loop first
        cur[t] = rp + 1;
    } else cur[t] = 0;
    __syncthreads();
    for (int i = lo + t; i < hi; i += 256) {
        int p = pairs[i];
        int pos = atomicAdd(&cur[p & 255], 1);
        adj[pos] = p >> 8;
    }
}

// ==================== gather: z_h[c] = sum_e w_eh * x[src_e][c] =============
// TWO nodes per 64-lane wave (one per half; lane = channel = edge slot).
// Weight phase: f32 exp weights + f32 den partials (independent adds, no
// dependency chain).  Record = float4 {byte_off, w01,w23,w45 as half2}.
// Gather body per wave-instr covers 2 edges: 1 ds_read_b128 + 1 ushort load
// + 3 pk_fma; trip padded x4 (4 loads in flight — R14 showed x2 regresses).
// Epilogue only: den partials packed to 3 half2 -> 15 shfl + 15 hadd2
// (was 30+30 f32); per-lane partials <=~1.4, sums <=~45 -> fp16-safe.
// No max-subtraction (scores are O(0.1); softmax is shift-invariant).
__global__ __launch_bounds__(256) void k_gat(
    const int* __restrict__ rowptr, const int* __restrict__ deg,
    const int* __restrict__ adj,
    const float* __restrict__ asrc, const float* __restrict__ adst,
    const __half* __restrict__ xp, __half* __restrict__ zn, int N)
{
    __shared__ float4 st[4][2][32];
    const int wv = threadIdx.x >> 6;
    const int lane = threadIdx.x & 63;
    const int half = lane >> 5;
    const int c = lane & 31;                  // channel == edge slot
    const int n = blockIdx.x * 8 + wv * 2 + half;
    const bool nvalid = (n < N);
    const int nsafe = nvalid ? n : 0;

    const float* adr = adst + (size_t)nsafe * 8;
    const float ad0 = adr[0], ad1 = adr[1], ad2 = adr[2];
    const float ad3 = adr[3], ad4 = adr[4], ad5 = adr[5];

    const int start = rowptr[nsafe];
    const int dg = nvalid ? deg[nsafe] : 1;
    const int dgmax = max(dg, __shfl_xor(dg, 32));
    const char* xcb = (const char*)xp + c * 2;

    __half2 acc0 = __float2half2_rn(0.f);
    __half2 acc1 = __float2half2_rn(0.f);
    __half2 acc2 = __float2half2_rn(0.f);
    float dl0 = 0.f, dl1 = 0.f, dl2 = 0.f, dl3 = 0.f, dl4 = 0.f, dl5 = 0.f;

    for (int base = 0; base < dgmax; base += 32) {
        const int rem = dg - base;
        const bool valid = nvalid && (c < rem);
        const int s = valid ? adj[start + base + c] : 0;
        const float4* a4 = (const float4*)(asrc + (size_t)s * 8);
        const float4 A = a4[0], Bv = a4[1];
        float v0 = A.x + ad0, v1 = A.y + ad1, v2 = A.z + ad2;
        float v3 = A.w + ad3, v4 = Bv.x + ad4, v5 = Bv.y + ad5;
        v0 = fmaxf(v0, NEG_SLOPE * v0); v1 = fmaxf(v1, NEG_SLOPE * v1);
        v2 = fmaxf(v2, NEG_SLOPE * v2); v3 = fmaxf(v3, NEG_SLOPE * v3);
        v4 = fmaxf(v4, NEG_SLOPE * v4); v5 = fmaxf(v5, NEG_SLOPE * v5);
        const float w0 = valid ? __expf(v0) : 0.f;
        const float w1 = valid ? __expf(v1) : 0.f;
        const float w2 = valid ? __expf(v2) : 0.f;
        const float w3 = valid ? __expf(v3) : 0.f;
        const float w4 = valid ? __expf(v4) : 0.f;
        const float w5 = valid ? __expf(v5) : 0.f;
        dl0 += w0; dl1 += w1; dl2 += w2; dl3 += w3; dl4 += w4; dl5 += w5;
        float4 rec;
        rec.x = __int_as_float(s * 64);       // byte offset of fp16 x row
        const __half2 w01 = __floats2half2_rn(w0, w1);
        const __half2 w23 = __floats2half2_rn(w2, w3);
        const __half2 w45 = __floats2half2_rn(w4, w5);
        rec.y = *(const float*)&w01;
        rec.z = *(const float*)&w23;
        rec.w = *(const float*)&w45;
        st[wv][half][c] = rec;                // all 64 lanes write own slot

        // gather this chunk; trip = max over both halves, padded x4; slots
        // past a node's rem carry zero weights, so they're harmless.
        const int cntw = min(32, dgmax - base);
        const int nh = (cntw + 3) & ~3;
        for (int i = 0; i < nh; i += 4) {
            #pragma unroll
            for (int q = 0; q < 4; ++q) {
                const float4 r = st[wv][half][i + q];
                const __half xval = *(const __half*)(xcb + __float_as_int(r.x));
                const __half2 xv2 = __half2half2(xval);
                acc0 = __hfma2(*(const __half2*)&r.y, xv2, acc0);
                acc1 = __hfma2(*(const __half2*)&r.z, xv2, acc1);
                acc2 = __hfma2(*(const __half2*)&r.w, xv2, acc2);
            }
        }
    }
    // denominators: pack to half2, reduce over the 32 edge-slots of MY half
    __half2 dlA = __floats2half2_rn(dl0, dl1);
    __half2 dlB = __floats2half2_rn(dl2, dl3);
    __half2 dlC = __floats2half2_rn(dl4, dl5);
    #pragma unroll
    for (int o = 1; o <= 16; o <<= 1) {
        int bA = __shfl_xor(*(const int*)&dlA, o);
        int bB = __shfl_xor(*(const int*)&dlB, o);
        int bC = __shfl_xor(*(const int*)&dlC, o);
        dlA = __hadd2(dlA, *(const __half2*)&bA);
        dlB = __hadd2(dlB, *(const __half2*)&bB);
        dlC = __hadd2(dlC, *(const __half2*)&bC);
    }
    if (nvalid) {
        const float r0 = 1.f / __low2float(dlA);
        const float r1 = 1.f / __high2float(dlA);
        const float r2 = 1.f / __low2float(dlB);
        const float r3 = 1.f / __high2float(dlB);
        const float r4 = 1.f / __low2float(dlC);
        const float r5 = 1.f / __high2float(dlC);
        __half* zr = zn + (size_t)n * 192 + c;
        zr[0]   = __float2half(__low2float(acc0)  * r0);
        zr[32]  = __float2half(__high2float(acc0) * r1);
        zr[64]  = __float2half(__low2float(acc1)  * r2);
        zr[96]  = __float2half(__high2float(acc1) * r3);
        zr[128] = __float2half(__low2float(acc2)  * r4);
        zr[160] = __float2half(__high2float(acc2) * r5);
    }
}

// ==================== post: y = (1/6) sum_h znorm_h . W_h + b ===============
// FUSE=0: also computes next layer's alphas from y in-LDS (fused prep) and
// writes fp16 y rows.  FUSE=1: fused MLP head + sigmoid.
template<int FUSE>
__global__ __launch_bounds__(192) void k_post(
    const __half* __restrict__ zn, const unsigned int* __restrict__ whalf,
    const float* __restrict__ bias, __half* __restrict__ yout,
    const float* __restrict__ wsd,
    float* __restrict__ asrc, float* __restrict__ adst,
    const int* __restrict__ user, const float* __restrict__ u_table,
    const float* __restrict__ weff, float* __restrict__ outp, int N)
{
    __shared__ unsigned int znl[TILE][96];
    __shared__ float part[TILE][192];
    __shared__ float ys[TILE][33];
    __shared__ float wsd_s[384];
    const int t = threadIdx.x;
    const int h = t >> 5, c = t & 31;
    const int n0 = blockIdx.x * TILE;

    const uint4* wq = (const uint4*)(whalf + (size_t)t * 16);
    const uint4 w0 = wq[0], w1 = wq[1], w2 = wq[2], w3 = wq[3];
    if (FUSE == 0)
        for (int i = t; i < 384; i += 192) wsd_s[i] = wsd[i];

    {   // stage znorm tile: 16 rows x 96 dwords; thread loads 8 dwords
        const int m = t / 12, slot = t - m * 12;
        const int n = n0 + m;
        if (n < N) {
            const uint4* src = (const uint4*)((const unsigned int*)zn
                               + (size_t)n * 96 + slot * 8);
            uint4 a = src[0], b = src[1];
            uint4* d = (uint4*)&znl[m][slot * 8];
            d[0] = a; d[1] = b;
        }
    }
    __syncthreads();

    #define DOT4(W) { \
        unsigned int zz0 = zp[0], zz1 = zp[1], zz2 = zp[2], zz3 = zp[3]; \
        acc2 = __hfma2(*(__half2*)&zz0, *(__half2*)&W.x, acc2); \
        acc2 = __hfma2(*(__half2*)&zz1, *(__half2*)&W.y, acc2); \
        acc2 = __hfma2(*(__half2*)&zz2, *(__half2*)&W.z, acc2); \
        acc2 = __hfma2(*(__half2*)&zz3, *(__half2*)&W.w, acc2); zp += 4; }

    #pragma unroll 4
    for (int m = 0; m < TILE; ++m) {
        const unsigned int* zp = &znl[m][h * 16];
        __half2 acc2 = __float2half2_rn(0.f);
        DOT4(w0) DOT4(w1) DOT4(w2) DOT4(w3)
        part[m][t] = __low2float(acc2) + __high2float(acc2);
    }
    #undef DOT4
    __syncthreads();

    #pragma unroll
    for (int mb = 0; mb < 3; ++mb) {
        const int m = mb * 6 + h;             // h in 0..5 -> m in 0..17
        const int n = n0 + m;
        if (m < TILE && n < N) {
            const float y = (part[m][c] + part[m][32 + c] + part[m][64 + c]
                           + part[m][96 + c] + part[m][128 + c]
                           + part[m][160 + c]) * (1.f / 6.f) + bias[c];
            if (FUSE == 0) {
                yout[(size_t)n * 32 + c] = __float2half(y);
                ys[m][c] = y;
            } else {
                const float u = u_table[(size_t)user[n] * 32 + c];
                float p = fmaf(y, weff[32 + c], u * weff[c]);
                #pragma unroll
                for (int o = 16; o > 0; o >>= 1) p += __shfl_xor(p, o);
                if (c == 0) outp[n] = 1.f / (1.f + __expf(-(p + weff[64])));
            }
        }
    }
    if (FUSE == 0) {                          // fused next-layer alpha prep
        __syncthreads();
        const int m = t / 12, j = t - m * 12;
        const int n = n0 + m;
        if (n < N) {
            const float* yr = ys[m];
            float a = 0.f;
            #pragma unroll
            for (int k = 0; k < 32; ++k) a = fmaf(yr[k], wsd_s[k * 12 + j], a);
            if (j < 6) asrc[(size_t)n * 8 + j] = a;
            else       adst[(size_t)n * 8 + (j - 6)] = a;
        }
    }
}

// ==================== launch ================================================

extern "C" void kernel_launch(void* const* d_in, const int* in_sizes, int n_in,
                              void* d_out, int out_size, void* d_ws, size_t ws_size,
                              hipStream_t stream)
{
    const int*   user    = (const int*)  d_in[0];
    const int*   item    = (const int*)  d_in[1];
    const int*   graph   = (const int*)  d_in[2];
    const float* u_table = (const float*)d_in[3];
    const float* i_table = (const float*)d_in[4];
    const float* W1      = (const float*)d_in[5];
    const float* a_src1  = (const float*)d_in[6];
    const float* a_dst1  = (const float*)d_in[7];
    const float* b1      = (const float*)d_in[8];
    const float* W2      = (const float*)d_in[9];
    const float* a_src2  = (const float*)d_in[10];
    const float* a_dst2  = (const float*)d_in[11];
    const float* b2      = (const float*)d_in[12];
    const float* lw1     = (const float*)d_in[13];
    const float* lb1     = (const float*)d_in[14];
    const float* lw2     = (const float*)d_in[15];
    const float* lb2     = (const float*)d_in[16];

    const int B  = in_sizes[0];
    const int N  = B;
    const int E  = in_sizes[2] / 2;
    const int Et = E + N;
    const int NBK = (N + 255) / 256;
    const int NBLK = (E + CHUNK - 1) / CHUNK;

    float* ws = (float*)d_ws;
    size_t off = 0;
    __half* xp1   = (__half*)(ws + off); off += (size_t)N * 16;  // N*32 halves
    __half* y1h   = (__half*)(ws + off); off += (size_t)N * 16;
    __half* zn    = (__half*)(ws + off); off += (size_t)N * 96;  // N*192 halves
    float* asrc   = ws + off; off += (size_t)N * 8;
    float* adst   = ws + off; off += (size_t)N * 8;
    float* wsd1   = ws + off; off += 384;
    float* wsd2   = ws + off; off += 384;
    float* weff   = ws + off; off += 128;
    unsigned int* whalf1 = (unsigned int*)(ws + off); off += 3072;
    unsigned int* whalf2 = (unsigned int*)(ws + off); off += 3072;
    int*   deg    = (int*)(ws + off); off += N;
    int*   rowptr = (int*)(ws + off); off += N;
    int*   bcnt   = (int*)(ws + off); off += NBK + 1;
    int*   bbase  = (int*)(ws + off); off += (size_t)NBLK * NBK;
    int*   adj    = (int*)(ws + off); off += Et + 2;
    int*   pairs  = (int*)(ws + off); off += E;

    const int ggrid = (N + 7) / 8;
    const int pgrid = (N + TILE - 1) / TILE;

    // L1: zero bcnt + setup (wsd, whalf, weff)
    hipLaunchKernelGGL(k_init, dim3(1), dim3(832), 0, stream,
        W1, a_src1, a_dst1, W2, a_src2, a_dst2,
        lw1, lb1, lw2, lb2, wsd1, wsd2, weff, whalf1, whalf2, bcnt, NBK);
    // L2: edge histogram + layer-1 prep (independent work, one dispatch)
    hipLaunchKernelGGL(k_hist_prep, dim3(NBLK + pgrid), dim3(256), 0, stream,
        graph, E, bcnt, bbase, NBK, NBLK,
        i_table, item, wsd1, xp1, asrc, adst, N);
    // L3: bin packed pairs (inline bucket scan)
    hipLaunchKernelGGL(k_bin2, dim3(NBLK), dim3(256), 0, stream,
        graph, E, bcnt, bbase, pairs, NBK);
    // L4: per-bucket CSR build (inline bucket scan)
    hipLaunchKernelGGL(k_build, dim3(NBK), dim3(256), 0, stream,
        pairs, bcnt, rowptr, deg, adj, N, NBK);
    // L5: layer-1 gather
    hipLaunchKernelGGL(k_gat, dim3(ggrid), dim3(256), 0, stream,
        rowptr, deg, adj, asrc, adst, xp1, zn, N);
    // L6: layer-1 post + fused layer-2 alpha prep
    hipLaunchKernelGGL(k_post<0>, dim3(pgrid), dim3(192), 0, stream,
        zn, whalf1, b1, y1h, wsd2, asrc, adst,
        (const int*)nullptr, (const float*)nullptr,
        (const float*)nullptr, (float*)nullptr, N);
    // L7: layer-2 gather
    hipLaunchKernelGGL(k_gat, dim3(ggrid), dim3(256), 0, stream,
        rowptr, deg, adj, asrc, adst, y1h, zn, N);
    // L8: layer-2 post + fused MLP head + sigmoid
    hipLaunchKernelGGL(k_post<1>, dim3(pgrid), dim3(192), 0, stream,
        zn, whalf2, b2, (__half*)nullptr, (const float*)nullptr,
        (float*)nullptr, (float*)nullptr,
        user, u_table, weff, (float*)d_out, N);
}